// Round 7
// baseline (177.503 us; speedup 1.0000x reference)
//
#include <hip/hip_runtime.h>
#include <math.h>

#define FEAT 256
#define HID  16
#define STEPS 10
#define GPACK_N (9*4*64*8)   // 8 feature chunks + chunk8 (Whh), 16x16x32 B-frag order

typedef unsigned short ushort_t;
typedef __attribute__((ext_vector_type(8)))  short  short8;
typedef __attribute__((ext_vector_type(4)))  float  floatx4;
typedef __attribute__((ext_vector_type(16))) float  floatx16;
typedef __attribute__((ext_vector_type(2)))  unsigned int uint2v;
typedef __attribute__((ext_vector_type(4)))  unsigned int uintx4;

__device__ __forceinline__ ushort_t f2bf_bits(float f) {
    union { float f; unsigned u; } cv; cv.f = f;
    unsigned u = cv.u;
    u = (u + 0x7FFFu + ((u >> 16) & 1u)) >> 16;   // RNE
    return (ushort_t)u;
}

__device__ __forceinline__ unsigned pk2bf(float lo, float hi) {
    unsigned r;
    asm("v_cvt_pk_bf16_f32 %0, %1, %2" : "=v"(r) : "v"(lo), "v"(hi));
    return r;
}

// relu two f32 then pack to bf16 pair
__device__ __forceinline__ unsigned relupk(float a, float b) {
    return pk2bf(fmaxf(a, 0.f), fmaxf(b, 0.f));
}

// split f32 into (hi_bf16, lo_bf16) packed dword: hi = truncate, lo = RNE(residual)
__device__ __forceinline__ unsigned packhl(float x) {
    unsigned u = __float_as_uint(x);
    float hi = __uint_as_float(u & 0xFFFF0000u);
    return pk2bf(hi, x - hi);
}

__global__ __launch_bounds__(256, 2) void march(
    const float* __restrict__ c2w, const float* __restrict__ intr,
    const float* __restrict__ uv,  const float* __restrict__ dep0,
    const float* __restrict__ Wphi, const float* __restrict__ bphi,
    const float* __restrict__ Wih,  const float* __restrict__ bih,
    const float* __restrict__ Whh,  const float* __restrict__ bhh,
    const float* __restrict__ Wout, const float* __restrict__ bout,
    float* __restrict__ out, int B, int N) {

    // LDS: 36864 + 20480 + 12288 + 1024 = 70656 B -> 2 blocks/CU
    __shared__ __align__(16) ushort_t Blds[GPACK_N];      // gate W fragments (9 chunks)
    __shared__ __align__(16) ushort_t Xlds[4][64][40];    // per-wave X chunk, 80B rows
    __shared__ __align__(16) ushort_t Hlds[4][64][24];    // per-wave h transpose, 48B rows
    __shared__ __align__(16) float    Sdls[4][64];        // per-wave sd broadcast

    int tid = threadIdx.x;
    int w = tid >> 6, l = tid & 63;
    int lc = l & 15, lg = l >> 4;
    int l31 = l & 31;
    bool hi32 = (l >= 32);
    int ray = blockIdx.x * 256 + tid;
    int BN = B * N;
    int b = ray / N;

    const float L = 1.4426950408889634f;   // log2(e)

    // ---- cooperative pack: gate weights -> Blds (16x16x32 B-frag order) ----
    // lane holds B[k = kc*32 + (lane>>4)*8 + e][col = n*16 + (lane&15)]
    for (int idx = tid; idx < GPACK_N; idx += 256) {
        int e    = idx & 7;
        int lane = (idx >> 3) & 63;
        int n    = (idx >> 9) & 3;
        int kc   = idx >> 11;
        int k    = kc * 32 + (lane >> 4) * 8 + e;
        int col  = n * 16 + (lane & 15);
        float v = 0.f;
        if (k < FEAT)                 v = Wih[col * FEAT + k];
        else if (k - FEAT < HID)      v = Whh[col * HID + (k - FEAT)];
        float sc = (col >= 32 && col < 48) ? (2.f * L) : L;  // g-gate pre-scaled 2log2e
        Blds[idx] = f2bf_bits(v * sc);
    }

    // ---- per-lane phi A-fragments (32x32x16): k multiplies [w0h,w0l,w1h,w1l,w2h,w2l,1,0]
    short8 phiA[8];
#pragma unroll
    for (int ft = 0; ft < 8; ++ft) {
        float q0 = 0.f, q1 = 0.f, q2 = 0.f, q3 = 0.f;
        if (!hi32) {
            int f = ft * 32 + l31;
            q0 = Wphi[f]; q1 = Wphi[FEAT + f]; q2 = Wphi[2 * FEAT + f]; q3 = bphi[f];
        }
        union { unsigned u[4]; short8 s; } cv;
        cv.u[0] = pk2bf(q0, q0); cv.u[1] = pk2bf(q1, q1);
        cv.u[2] = pk2bf(q2, q2); cv.u[3] = pk2bf(q3, 0.f);
        phiA[ft] = cv.s;
    }

    // ---- gate biases (f32, pre-scaled), go into the accumulator init ----
    float gbv[4];
#pragma unroll
    for (int n = 0; n < 4; ++n) {
        int col = n * 16 + lc;
        float sc = (n == 2) ? (2.f * L) : L;
        gbv[n] = sc * (bih[col] + bhh[col]);
    }
    float wj = Wout[lc];
    float bo = bout[0];

    // ---- ray geometry ----
    const float* M = c2w + b * 16;
    float R00 = M[0], R01 = M[1], R02 = M[2], t0 = M[3];
    float R10 = M[4], R11 = M[5], R12 = M[6], t1 = M[7];
    float R20 = M[8], R21 = M[9], R22 = M[10], t2 = M[11];
    const float* Kc = intr + b * 9;
    float fx = Kc[0], cx = Kc[2], fy = Kc[4], cy = Kc[5];

    float u = uv[ray * 2 + 0];
    float v = uv[ray * 2 + 1];
    float d0 = dep0[ray];

    float xl = (u - cx) / fx;
    float yl = (v - cy) / fy;
    float dx = R00 * xl + R01 * yl + R02;
    float dy = R10 * xl + R11 * yl + R12;
    float dz = R20 * xl + R21 * yl + R22;
    float invn = rsqrtf(dx * dx + dy * dy + dz * dz);
    float rdx = dx * invn, rdy = dy * invn, rdz = dz * invn;
    float w0 = fmaf(dx, d0, t0);
    float w1 = fmaf(dy, d0, t1);
    float w2 = fmaf(dz, d0, t2);

    // zero-init Hlds row (h0 = 0; no bias slot anymore)
    {
        uintx4 z4 = {0u, 0u, 0u, 0u};
        uintx4* hr = (uintx4*)&Hlds[w][l][0];
        hr[0] = z4; hr[1] = z4; hr[2] = z4;
    }

    short8 z8 = {0, 0, 0, 0, 0, 0, 0, 0};

    float cst[HID];
#pragma unroll
    for (int j = 0; j < HID; ++j) cst[j] = 0.f;

    __syncthreads();  // Blds packed, Hlds zeroed

#pragma unroll 1
    for (int s = 0; s < STEPS; ++s) {
        // ---- world B-fragments (32x32x16), hi/lo bf16 split ----
        float s0 = __shfl(w0, l31 + 32);
        float s1 = __shfl(w1, l31 + 32);
        float s2 = __shfl(w2, l31 + 32);
        short8 bw0, bw1;
        {
            unsigned a0 = hi32 ? 0u : packhl(w0);
            unsigned a1 = hi32 ? 0u : packhl(w1);
            unsigned a2 = hi32 ? 0u : packhl(w2);
            unsigned a3 = hi32 ? 0u : 0x00003F80u;
            unsigned c0 = hi32 ? 0u : packhl(s0);
            unsigned c1 = hi32 ? 0u : packhl(s1);
            unsigned c2 = hi32 ? 0u : packhl(s2);
            union { unsigned u[4]; short8 s; } cv0, cv1;
            cv0.u[0] = a0; cv0.u[1] = a1; cv0.u[2] = a2; cv0.u[3] = a3;
            cv1.u[0] = c0; cv1.u[1] = c1; cv1.u[2] = c2; cv1.u[3] = a3;
            bw0 = cv0.s; bw1 = cv1.s;
        }

        // ---- accumulators start at the (f32) biases ----
        floatx4 acc[4][4];
#pragma unroll
        for (int m = 0; m < 4; ++m)
#pragma unroll
            for (int n = 0; n < 4; ++n)
                acc[m][n] = (floatx4){gbv[n], gbv[n], gbv[n], gbv[n]};

        // ---- 8 feature chunks: phi MFMA -> relu/pack -> LDS transpose -> gates MFMA
#pragma unroll
        for (int kc = 0; kc < 8; ++kc) {
            floatx16 zz = (floatx16){0.f,0.f,0.f,0.f,0.f,0.f,0.f,0.f,
                                     0.f,0.f,0.f,0.f,0.f,0.f,0.f,0.f};
            floatx16 p0 = __builtin_amdgcn_mfma_f32_32x32x16_bf16(phiA[kc], bw0, zz, 0, 0, 0);
            floatx16 p1 = __builtin_amdgcn_mfma_f32_32x32x16_bf16(phiA[kc], bw1, zz, 0, 0, 0);
            {
                uint2v* q0 = (uint2v*)&Xlds[w][l31][4 * (int)hi32];
                uint2v d;
                d.x = relupk(p0[0],  p0[1]);  d.y = relupk(p0[2],  p0[3]);  q0[0] = d;
                d.x = relupk(p0[4],  p0[5]);  d.y = relupk(p0[6],  p0[7]);  q0[2] = d;
                d.x = relupk(p0[8],  p0[9]);  d.y = relupk(p0[10], p0[11]); q0[4] = d;
                d.x = relupk(p0[12], p0[13]); d.y = relupk(p0[14], p0[15]); q0[6] = d;
                uint2v* q1 = (uint2v*)&Xlds[w][32 + l31][4 * (int)hi32];
                d.x = relupk(p1[0],  p1[1]);  d.y = relupk(p1[2],  p1[3]);  q1[0] = d;
                d.x = relupk(p1[4],  p1[5]);  d.y = relupk(p1[6],  p1[7]);  q1[2] = d;
                d.x = relupk(p1[8],  p1[9]);  d.y = relupk(p1[10], p1[11]); q1[4] = d;
                d.x = relupk(p1[12], p1[13]); d.y = relupk(p1[14], p1[15]); q1[6] = d;
            }
            short8 af[4], bf[4];
#pragma unroll
            for (int m = 0; m < 4; ++m)
                af[m] = *(const short8*)&Xlds[w][16 * m + lc][lg * 8];
#pragma unroll
            for (int n = 0; n < 4; ++n)
                bf[n] = *(const short8*)&Blds[((kc * 4 + n) * 64 + l) * 8];
#pragma unroll
            for (int m = 0; m < 4; ++m)
#pragma unroll
                for (int n = 0; n < 4; ++n)
                    acc[m][n] = __builtin_amdgcn_mfma_f32_16x16x32_bf16(
                        af[m], bf[n], acc[m][n], 0, 0, 0);
        }

        // ---- chunk 8: h_{s-1} @ Whh^T, A-fragments re-read from Hlds ----
        {
            short8 af[4], bf8[4];
#pragma unroll
            for (int m = 0; m < 4; ++m)
                af[m] = (lg < 2) ? *(const short8*)&Hlds[w][16 * m + lc][8 * lg] : z8;
#pragma unroll
            for (int n = 0; n < 4; ++n)
                bf8[n] = *(const short8*)&Blds[((32 + n) * 64 + l) * 8];
#pragma unroll
            for (int m = 0; m < 4; ++m)
#pragma unroll
                for (int n = 0; n < 4; ++n)
                    acc[m][n] = __builtin_amdgcn_mfma_f32_16x16x32_bf16(
                        af[m], bf8[n], acc[m][n], 0, 0, 0);
        }

        // ---- LSTM elementwise (gates pre-scaled by log2e / 2log2e) ----
        const float L2 = 2.8853900817779268f;  // 2*log2(e)
        float sp[4][4];
#pragma unroll
        for (int m = 0; m < 4; ++m) {
#pragma unroll
            for (int i = 0; i < 4; ++i) {
                float ig = __builtin_amdgcn_rcpf(1.f + __builtin_amdgcn_exp2f(-acc[m][0][i]));
                float fg = __builtin_amdgcn_rcpf(1.f + __builtin_amdgcn_exp2f(-acc[m][1][i]));
                float gg = fmaf(-2.f, __builtin_amdgcn_rcpf(1.f + __builtin_amdgcn_exp2f(acc[m][2][i])), 1.f);
                float og = __builtin_amdgcn_rcpf(1.f + __builtin_amdgcn_exp2f(-acc[m][3][i]));
                int idx = m * 4 + i;
                float cn = fmaf(fg, cst[idx], ig * gg);
                cst[idx] = cn;
                float tc = fmaf(-2.f, __builtin_amdgcn_rcpf(1.f + __builtin_amdgcn_exp2f(L2 * cn)), 1.f);
                float hn = og * tc;
                Hlds[w][16 * m + 4 * lg + i][lc] = (ushort_t)pk2bf(hn, hn);
                sp[m][i] = hn * wj;
            }
        }
        // ---- sd reduce over the 16 lanes (hidden dims) sharing the same rays ----
#pragma unroll
        for (int r = 1; r < 16; r <<= 1) {
#pragma unroll
            for (int m = 0; m < 4; ++m)
#pragma unroll
                for (int i = 0; i < 4; ++i)
                    sp[m][i] += __shfl_xor(sp[m][i], r, 64);
        }
        if (lc == 0) {
#pragma unroll
            for (int m = 0; m < 4; ++m) {
                floatx4 vv = {sp[m][0], sp[m][1], sp[m][2], sp[m][3]};
                *(floatx4*)&Sdls[w][16 * m + 4 * lg] = vv;
            }
        }

        float sdv = Sdls[w][l] + bo;
        w0 = fmaf(rdx, sdv, w0);
        w1 = fmaf(rdy, sdv, w1);
        w2 = fmaf(rdz, sdv, w2);
    }

    int base = ray * 3;
    out[base + 0] = w0;
    out[base + 1] = w1;
    out[base + 2] = w2;
    float dd = R02 * (w0 - t0) + R12 * (w1 - t1) + R22 * (w2 - t2);
    out[BN * 3 + ray] = dd;
}

extern "C" void kernel_launch(void* const* d_in, const int* in_sizes, int n_in,
                              void* d_out, int out_size, void* d_ws, size_t ws_size,
                              hipStream_t stream) {
    const float* c2w  = (const float*)d_in[0];
    const float* intr = (const float*)d_in[1];
    const float* uv   = (const float*)d_in[2];
    const float* dep  = (const float*)d_in[3];
    const float* Wphi = (const float*)d_in[4];
    const float* bphi = (const float*)d_in[5];
    const float* Wih  = (const float*)d_in[6];
    const float* bih  = (const float*)d_in[7];
    const float* Whh  = (const float*)d_in[8];
    const float* bhh  = (const float*)d_in[9];
    const float* Wout = (const float*)d_in[10];
    const float* bout = (const float*)d_in[11];
    float* out = (float*)d_out;

    int B = in_sizes[0] / 16;
    int BN = in_sizes[3];
    int N = BN / B;
    int blocks = (BN + 255) / 256;

    march<<<blocks, 256, 0, stream>>>(c2w, intr, uv, dep,
                                      Wphi, bphi, Wih, bih, Whh, bhh, Wout, bout,
                                      out, B, N);
}

// Round 8
// 141.446 us; speedup vs baseline: 1.2549x; 1.2549x over previous
//
#include <hip/hip_runtime.h>
#include <math.h>

#define FEAT 256
#define HID  16
#define STEPS 10

// d_ws ushort layout (written by prep each launch):
//   [0, 16384)      : AW  - Wih A-frags (32x32x16): [kc][gt][kt][lane][e]
//   [16384, 20480)  : PHI - phi A-frags (32x32x16): [ft][lane][e]
//   [20480, 21504)  : WHA - Whh A-frags (32x32x16): [gt][lane][e]
#define AW_N    16384
#define PHI_OFF 16384
#define PHI_N   4096
#define WHA_OFF 20480
#define WHA_N   1024
#define TOT_N   21504

typedef unsigned short ushort_t;
typedef __attribute__((ext_vector_type(8)))  short  short8;
typedef __attribute__((ext_vector_type(16))) float  floatx16;
typedef __attribute__((ext_vector_type(4)))  unsigned int uintx4;

__device__ __forceinline__ ushort_t f2bf_bits(float f) {
    union { float f; unsigned u; } cv; cv.f = f;
    unsigned u = cv.u;
    u = (u + 0x7FFFu + ((u >> 16) & 1u)) >> 16;   // RNE
    return (ushort_t)u;
}

__device__ __forceinline__ unsigned pk2bf(float lo, float hi) {
    unsigned r;
    asm("v_cvt_pk_bf16_f32 %0, %1, %2" : "=v"(r) : "v"(lo), "v"(hi));
    return r;
}

__device__ __forceinline__ unsigned relupk(float a, float b) {
    return pk2bf(fmaxf(a, 0.f), fmaxf(b, 0.f));
}

// split f32 into (hi_bf16, lo_bf16) packed dword
__device__ __forceinline__ unsigned packhl(float x) {
    unsigned u = __float_as_uint(x);
    float hi = __uint_as_float(u & 0xFFFF0000u);
    return pk2bf(hi, x - hi);
}

// a' : lanes<32 keep a, lanes>=32 get b[l-32]   (r0)
// b' : lanes<32 get a[l+32], lanes>=32 keep b   (r1)
__device__ __forceinline__ void plswap(unsigned &a, unsigned &b) {
#if __has_builtin(__builtin_amdgcn_permlane32_swap)
    auto r = __builtin_amdgcn_permlane32_swap(a, b, false, false);
    a = (unsigned)r[0]; b = (unsigned)r[1];
#else
    unsigned xa = (unsigned)__shfl_xor((int)a, 32, 64);
    unsigned xb = (unsigned)__shfl_xor((int)b, 32, 64);
    bool hi = (threadIdx.x & 63) >= 32;
    unsigned na = hi ? xb : a;
    unsigned nb = hi ? b : xa;
    a = na; b = nb;
#endif
}

__device__ __forceinline__ short8 mk8(unsigned a, unsigned b, unsigned c, unsigned d) {
    union { unsigned u[4]; short8 s; } cv;
    cv.u[0] = a; cv.u[1] = b; cv.u[2] = c; cv.u[3] = d;
    return cv.s;
}

// ---------------- prep: pack weight fragments (parallel) ----------------
__global__ void prep(const float* __restrict__ Wphi, const float* __restrict__ bphi,
                     const float* __restrict__ Wih,  const float* __restrict__ Whh,
                     void* __restrict__ ws) {
    int idx = blockIdx.x * 256 + threadIdx.x;
    const float L = 1.4426950408889634f;  // log2(e)
    ushort_t* p = (ushort_t*)ws;
    if (idx < AW_N) {
        // A[row=gate][k=feat], lane holds row=gt*32+(l&31), k=kt*16+(l>>5)*8+e
        int e    = idx & 7;
        int lane = (idx >> 3) & 63;
        int kt   = (idx >> 9) & 1;
        int gt   = (idx >> 10) & 1;
        int kc   = idx >> 11;
        int gate = gt * 32 + (lane & 31);
        int feat = kc * 32 + kt * 16 + (lane >> 5) * 8 + e;
        float sc = (gate >= 32 && gate < 48) ? (2.f * L) : L;   // g-gate: 2log2e
        p[idx] = f2bf_bits(Wih[gate * FEAT + feat] * sc);
    } else if (idx < WHA_OFF) {
        // phi A-frag: A[row=feat][k], k multiplies [w0h,w0l,w1h,w1l,w2h,w2l,1,0]
        int j    = idx - PHI_OFF;
        int e    = j & 7;
        int lane = (j >> 3) & 63;
        int ft   = j >> 9;
        float v = 0.f;
        if (lane < 32) {
            int f = ft * 32 + (lane & 31);
            if (e < 6)       v = Wphi[(e >> 1) * FEAT + f];
            else if (e == 6) v = bphi[f];
        }
        p[idx] = f2bf_bits(v);
    } else if (idx < TOT_N) {
        // Whh A-frag: A[row=gate][k=hidden]
        int j    = idx - WHA_OFF;
        int e    = j & 7;
        int lane = (j >> 3) & 63;
        int gt   = j >> 9;
        int gate = gt * 32 + (lane & 31);
        int k    = (lane >> 5) * 8 + e;
        float sc = (gate >= 32 && gate < 48) ? (2.f * L) : L;
        p[idx] = f2bf_bits(Whh[gate * HID + k] * sc);
    }
}

// ---------------- main kernel ----------------
__global__ __launch_bounds__(256, 2) void march(
    const float* __restrict__ c2w, const float* __restrict__ intr,
    const float* __restrict__ uv,  const float* __restrict__ dep0,
    const void* __restrict__ ws,
    const float* __restrict__ bih, const float* __restrict__ bhh,
    const float* __restrict__ Wout, const float* __restrict__ bout,
    float* __restrict__ out, int B, int N) {

    __shared__ __align__(16) ushort_t Slds[AW_N + PHI_N];   // 40 KB

    int tid = threadIdx.x;
    int l = tid & 63;
    int l31 = l & 31;
    bool hi32 = (l >= 32);
    int ray = blockIdx.x * 256 + tid;
    int BN = B * N;
    int b = ray / N;

    const float L = 1.4426950408889634f;

    // stage AW + PHI fragments into LDS (coalesced, conflict-free)
    {
        const uintx4* src = (const uintx4*)ws;
        uintx4* dst = (uintx4*)Slds;
        for (int i = tid; i < (AW_N + PHI_N) / 8; i += 256) dst[i] = src[i];
    }
    const short8* aw8 = (const short8*)Slds;

    // Whh A-frags from global (one-time)
    short8 whA0, whA1;
    {
        const short8* wha = (const short8*)((const ushort_t*)ws + WHA_OFF);
        whA0 = wha[l];
        whA1 = wha[64 + l];
    }

    // per-lane Wout slice: j = (q&3) + 4*hi32 + 8*(q>>2)
    float wjv[8];
#pragma unroll
    for (int q = 0; q < 8; ++q) wjv[q] = Wout[(q & 3) + 4 * (int)hi32 + 8 * (q >> 2)];
    float bo = bout[0];

    // gate biases in C/D layout (f32, pre-scaled)
    floatx16 gb0, gb1;
#pragma unroll
    for (int r = 0; r < 16; ++r) {
        int loc = (r & 3) + 8 * (r >> 2) + 4 * (int)hi32;
        gb0[r] = L * (bih[loc] + bhh[loc]);                       // gates 0-31 (i,f)
        float sc1 = (r < 8) ? (2.f * L) : L;                      // 32-47 g, 48-63 o
        gb1[r] = sc1 * (bih[32 + loc] + bhh[32 + loc]);
    }

    // ray geometry
    const float* M = c2w + b * 16;
    float R00 = M[0], R01 = M[1], R02 = M[2], t0 = M[3];
    float R10 = M[4], R11 = M[5], R12 = M[6], t1 = M[7];
    float R20 = M[8], R21 = M[9], R22 = M[10], t2 = M[11];
    const float* Kc = intr + b * 9;
    float fx = Kc[0], cx = Kc[2], fy = Kc[4], cy = Kc[5];

    float u = uv[ray * 2 + 0];
    float v = uv[ray * 2 + 1];
    float d0 = dep0[ray];

    float xl = (u - cx) / fx;
    float yl = (v - cy) / fy;
    float dx = R00 * xl + R01 * yl + R02;
    float dy = R10 * xl + R11 * yl + R12;
    float dz = R20 * xl + R21 * yl + R22;
    float invn = rsqrtf(dx * dx + dy * dy + dz * dz);
    float rdx = dx * invn, rdy = dy * invn, rdz = dz * invn;
    float w0 = fmaf(dx, d0, t0);
    float w1 = fmaf(dy, d0, t1);
    float w2 = fmaf(dz, d0, t2);

    short8 z8 = {0, 0, 0, 0, 0, 0, 0, 0};
    short8 hB0 = z8, hB1 = z8;      // h_{s-1} B-frags (rt0, rt1)

    float cst[16];                   // c-state: [rt*8 + q]
#pragma unroll
    for (int j = 0; j < 16; ++j) cst[j] = 0.f;

    __syncthreads();  // Slds staged

#pragma unroll 1
    for (int s = 0; s < STEPS; ++s) {
        // ---- world B-fragments (32x32x16), hi/lo bf16 split ----
        float s0 = __shfl(w0, l31 + 32);
        float s1 = __shfl(w1, l31 + 32);
        float s2 = __shfl(w2, l31 + 32);
        short8 bw0, bw1;
        {
            unsigned a0 = hi32 ? 0u : packhl(w0);
            unsigned a1 = hi32 ? 0u : packhl(w1);
            unsigned a2 = hi32 ? 0u : packhl(w2);
            unsigned a3 = hi32 ? 0u : 0x00003F80u;
            unsigned c0 = hi32 ? 0u : packhl(s0);
            unsigned c1 = hi32 ? 0u : packhl(s1);
            unsigned c2 = hi32 ? 0u : packhl(s2);
            bw0 = mk8(a0, a1, a2, a3);
            bw1 = mk8(c0, c1, c2, a3);
        }

        floatx16 a00 = gb0, a01 = gb0;   // [gt][rt]
        floatx16 a10 = gb1, a11 = gb1;

        floatx16 zz = (floatx16){0.f,0.f,0.f,0.f,0.f,0.f,0.f,0.f,
                                 0.f,0.f,0.f,0.f,0.f,0.f,0.f,0.f};

        // ---- 8 feature chunks: phi MFMA -> relu/pack -> permlane swap -> gates MFMA
#pragma unroll
        for (int kc = 0; kc < 8; ++kc) {
            short8 aphi = aw8[(AW_N / 8) + kc * 64 + l];
            floatx16 p0 = __builtin_amdgcn_mfma_f32_32x32x16_bf16(aphi, bw0, zz, 0, 0, 0);
            floatx16 p1 = __builtin_amdgcn_mfma_f32_32x32x16_bf16(aphi, bw1, zz, 0, 0, 0);

            unsigned P0[8], P1[8];
#pragma unroll
            for (int q = 0; q < 8; ++q) {
                P0[q] = relupk(p0[2 * q], p0[2 * q + 1]);
                P1[q] = relupk(p1[2 * q], p1[2 * q + 1]);
            }
            // phi-D -> gates-B transpose within lane pairs
            plswap(P0[0], P0[2]); plswap(P0[1], P0[3]);
            plswap(P0[4], P0[6]); plswap(P0[5], P0[7]);
            plswap(P1[0], P1[2]); plswap(P1[1], P1[3]);
            plswap(P1[4], P1[6]); plswap(P1[5], P1[7]);
            short8 b00 = mk8(P0[0], P0[1], P0[2], P0[3]);   // rt0, k 0-15
            short8 b01 = mk8(P0[4], P0[5], P0[6], P0[7]);   // rt0, k 16-31
            short8 b10 = mk8(P1[0], P1[1], P1[2], P1[3]);
            short8 b11 = mk8(P1[4], P1[5], P1[6], P1[7]);

            short8 wA00 = aw8[(kc * 4 + 0) * 64 + l];       // gt0 kt0
            short8 wA01 = aw8[(kc * 4 + 1) * 64 + l];       // gt0 kt1
            short8 wA10 = aw8[(kc * 4 + 2) * 64 + l];       // gt1 kt0
            short8 wA11 = aw8[(kc * 4 + 3) * 64 + l];       // gt1 kt1

            a00 = __builtin_amdgcn_mfma_f32_32x32x16_bf16(wA00, b00, a00, 0, 0, 0);
            a00 = __builtin_amdgcn_mfma_f32_32x32x16_bf16(wA01, b01, a00, 0, 0, 0);
            a10 = __builtin_amdgcn_mfma_f32_32x32x16_bf16(wA10, b00, a10, 0, 0, 0);
            a10 = __builtin_amdgcn_mfma_f32_32x32x16_bf16(wA11, b01, a10, 0, 0, 0);
            a01 = __builtin_amdgcn_mfma_f32_32x32x16_bf16(wA00, b10, a01, 0, 0, 0);
            a01 = __builtin_amdgcn_mfma_f32_32x32x16_bf16(wA01, b11, a01, 0, 0, 0);
            a11 = __builtin_amdgcn_mfma_f32_32x32x16_bf16(wA10, b10, a11, 0, 0, 0);
            a11 = __builtin_amdgcn_mfma_f32_32x32x16_bf16(wA11, b11, a11, 0, 0, 0);
        }

        // ---- recurrence: gates += h_{s-1} @ Whh^T ----
        a00 = __builtin_amdgcn_mfma_f32_32x32x16_bf16(whA0, hB0, a00, 0, 0, 0);
        a10 = __builtin_amdgcn_mfma_f32_32x32x16_bf16(whA1, hB0, a10, 0, 0, 0);
        a01 = __builtin_amdgcn_mfma_f32_32x32x16_bf16(whA0, hB1, a01, 0, 0, 0);
        a11 = __builtin_amdgcn_mfma_f32_32x32x16_bf16(whA1, hB1, a11, 0, 0, 0);

        // ---- LSTM elementwise: lane owns rays (l31, 32+l31) x 8 hidden dims ----
        const float L2 = 2.8853900817779268f;  // 2*log2(e)
        float h0[8], h1[8];
#pragma unroll
        for (int q = 0; q < 8; ++q) {
            {   // rt0
                float ig = __builtin_amdgcn_rcpf(1.f + __builtin_amdgcn_exp2f(-a00[q]));
                float fg = __builtin_amdgcn_rcpf(1.f + __builtin_amdgcn_exp2f(-a00[8 + q]));
                float gg = fmaf(-2.f, __builtin_amdgcn_rcpf(1.f + __builtin_amdgcn_exp2f(a10[q])), 1.f);
                float og = __builtin_amdgcn_rcpf(1.f + __builtin_amdgcn_exp2f(-a10[8 + q]));
                float cn = fmaf(fg, cst[q], ig * gg);
                cst[q] = cn;
                float tc = fmaf(-2.f, __builtin_amdgcn_rcpf(1.f + __builtin_amdgcn_exp2f(L2 * cn)), 1.f);
                h0[q] = og * tc;
            }
            {   // rt1
                float ig = __builtin_amdgcn_rcpf(1.f + __builtin_amdgcn_exp2f(-a01[q]));
                float fg = __builtin_amdgcn_rcpf(1.f + __builtin_amdgcn_exp2f(-a01[8 + q]));
                float gg = fmaf(-2.f, __builtin_amdgcn_rcpf(1.f + __builtin_amdgcn_exp2f(a11[q])), 1.f);
                float og = __builtin_amdgcn_rcpf(1.f + __builtin_amdgcn_exp2f(-a11[8 + q]));
                float cn = fmaf(fg, cst[8 + q], ig * gg);
                cst[8 + q] = cn;
                float tc = fmaf(-2.f, __builtin_amdgcn_rcpf(1.f + __builtin_amdgcn_exp2f(L2 * cn)), 1.f);
                h1[q] = og * tc;
            }
        }

        // ---- sd = h . Wout : per-lane partial + one xor-32 add ----
        float sd0 = 0.f, sd1 = 0.f;
#pragma unroll
        for (int q = 0; q < 8; ++q) {
            sd0 = fmaf(h0[q], wjv[q], sd0);
            sd1 = fmaf(h1[q], wjv[q], sd1);
        }
        sd0 += __shfl_xor(sd0, 32, 64);
        sd1 += __shfl_xor(sd1, 32, 64);
        float sdv = (hi32 ? sd1 : sd0) + bo;

        // ---- pack h -> B-frags for next step's recurrence ----
        {
            unsigned QA = pk2bf(h0[0], h0[1]), QB = pk2bf(h0[2], h0[3]);
            unsigned QC = pk2bf(h0[4], h0[5]), QD = pk2bf(h0[6], h0[7]);
            plswap(QA, QC); plswap(QB, QD);
            hB0 = mk8(QA, QB, QC, QD);
            unsigned RA = pk2bf(h1[0], h1[1]), RB = pk2bf(h1[2], h1[3]);
            unsigned RC = pk2bf(h1[4], h1[5]), RD = pk2bf(h1[6], h1[7]);
            plswap(RA, RC); plswap(RB, RD);
            hB1 = mk8(RA, RB, RC, RD);
        }

        w0 = fmaf(rdx, sdv, w0);
        w1 = fmaf(rdy, sdv, w1);
        w2 = fmaf(rdz, sdv, w2);
    }

    int base = ray * 3;
    out[base + 0] = w0;
    out[base + 1] = w1;
    out[base + 2] = w2;
    float dd = R02 * (w0 - t0) + R12 * (w1 - t1) + R22 * (w2 - t2);
    out[BN * 3 + ray] = dd;
}

extern "C" void kernel_launch(void* const* d_in, const int* in_sizes, int n_in,
                              void* d_out, int out_size, void* d_ws, size_t ws_size,
                              hipStream_t stream) {
    const float* c2w  = (const float*)d_in[0];
    const float* intr = (const float*)d_in[1];
    const float* uv   = (const float*)d_in[2];
    const float* dep  = (const float*)d_in[3];
    const float* Wphi = (const float*)d_in[4];
    const float* bphi = (const float*)d_in[5];
    const float* Wih  = (const float*)d_in[6];
    const float* bih  = (const float*)d_in[7];
    const float* Whh  = (const float*)d_in[8];
    const float* bhh  = (const float*)d_in[9];
    const float* Wout = (const float*)d_in[10];
    const float* bout = (const float*)d_in[11];
    float* out = (float*)d_out;

    int B = in_sizes[0] / 16;
    int BN = in_sizes[3];
    int N = BN / B;
    int blocks = (BN + 255) / 256;

    prep<<<(TOT_N + 255) / 256, 256, 0, stream>>>(Wphi, bphi, Wih, Whh, d_ws);
    march<<<blocks, 256, 0, stream>>>(c2w, intr, uv, dep, d_ws,
                                      bih, bhh, Wout, bout, out, B, N);
}